// Round 2
// baseline (2028.472 us; speedup 1.0000x reference)
//
#include <hip/hip_runtime.h>

typedef unsigned short u16;
typedef unsigned int u32;

#define NPTS 131072
#define CD 128
#define KOFF 27
#define MMAP 65536
#define LDAB 136   // LDS row stride (u16) for A/B tiles: 128+8

__device__ __forceinline__ u16 f2bf(float f) {  // f32 -> bf16 RNE
  u32 u = __float_as_uint(f);
  u32 r = (u + 0x7fffu + ((u >> 16) & 1u)) >> 16;
  return (u16)r;
}

typedef __attribute__((ext_vector_type(8))) short bf16x8;
typedef __attribute__((ext_vector_type(4))) float f32x4;

// ---------------- dtype conversion ----------------
__global__ __launch_bounds__(256) void k_convert_x(const float* __restrict__ x,
                                                   u16* __restrict__ xb) {
  long i = ((long)blockIdx.x * 256 + threadIdx.x) * 8;
  float4 a = *(const float4*)(x + i);
  float4 b = *(const float4*)(x + i + 4);
  uint4 v;
  v.x = f2bf(a.x) | ((u32)f2bf(a.y) << 16);
  v.y = f2bf(a.z) | ((u32)f2bf(a.w) << 16);
  v.z = f2bf(b.x) | ((u32)f2bf(b.y) << 16);
  v.w = f2bf(b.z) | ((u32)f2bf(b.w) << 16);
  *(uint4*)(xb + i) = v;
}

// W [K][ci][co] f32 -> Wb [K][co][ci] bf16
__global__ __launch_bounds__(256) void k_convert_w(const float* __restrict__ W,
                                                   u16* __restrict__ Wb) {
  int idx = blockIdx.x * 256 + threadIdx.x;
  if (idx >= KOFF * 2048) return;
  int k = idx >> 11;
  int rem = idx & 2047;
  int co = rem >> 4;
  int cc = rem & 15;
  const float* ws = W + (long)k * (CD * CD) + (long)(cc * 8) * CD + co;
  u16 t[8];
#pragma unroll
  for (int j = 0; j < 8; ++j) t[j] = f2bf(ws[j * CD]);
  uint4 v;
  v.x = t[0] | ((u32)t[1] << 16);
  v.y = t[2] | ((u32)t[3] << 16);
  v.z = t[4] | ((u32)t[5] << 16);
  v.w = t[6] | ((u32)t[7] << 16);
  ((uint4*)Wb)[idx] = v;
}

// ---------------- gather-GEMM with direct f32 atomic scatter-add epilogue ----------------
// One dispatch covers all 27 k-offsets: block b -> k = b>>10, m-tile = (b&1023)*64.
// Epilogue adds straight from MFMA accumulators into acc[mo[entry]] via global_atomic_add_f32:
// no sort, no contrib buffer, no bf16 quantization of partial sums.
__global__ __launch_bounds__(256) void k_gemm4(const u16* __restrict__ src,
                                               const u16* __restrict__ Wb,
                                               const int* __restrict__ mi,
                                               const int* __restrict__ mo,
                                               float* __restrict__ acc) {
  __shared__ u16 As[64 * LDAB];
  __shared__ u16 Bs[128 * LDAB];
  __shared__ u32 sin[64];
  __shared__ u32 srow[64];
  const int t = threadIdx.x;
  const int b = blockIdx.x;
  const int klocal = b >> 10;
  const int i0 = klocal * MMAP + (b & 1023) * 64;

  if (t < 64) {
    sin[t] = (u32)mi[i0 + t];
    srow[t] = (u32)mo[i0 + t];
  }
  const uint4* wsrc = (const uint4*)(Wb + (long)klocal * (CD * CD));
#pragma unroll
  for (int i = 0; i < 8; ++i) {
    int q = i * 256 + t;
    int co = q >> 4, cc = q & 15;
    *(uint4*)&Bs[co * LDAB + cc * 8] = wsrc[q];
  }
  __syncthreads();
#pragma unroll
  for (int i = 0; i < 4; ++i) {
    int q = i * 256 + t;
    int r = q >> 4, cc = q & 15;
    long row = sin[r];
    *(uint4*)&As[r * LDAB + cc * 8] = ((const uint4*)(src + row * CD))[cc];
  }
  __syncthreads();

  const int wave = t >> 6, lane = t & 63;
  const int lr = lane & 15, quad = lane >> 4;
  const int wm = (wave & 1) * 32;
  const int wn = (wave >> 1) * 64;
  f32x4 C[2][4] = {};
#pragma unroll
  for (int kk = 0; kk < 4; ++kk) {
    bf16x8 a[2], bfr[4];
#pragma unroll
    for (int mt = 0; mt < 2; ++mt)
      a[mt] = *(const bf16x8*)&As[(wm + mt * 16 + lr) * LDAB + (kk * 4 + quad) * 8];
#pragma unroll
    for (int nt = 0; nt < 4; ++nt)
      bfr[nt] = *(const bf16x8*)&Bs[(wn + nt * 16 + lr) * LDAB + (kk * 4 + quad) * 8];
#pragma unroll
    for (int mt = 0; mt < 2; ++mt)
#pragma unroll
      for (int nt = 0; nt < 4; ++nt)
        C[mt][nt] = __builtin_amdgcn_mfma_f32_16x16x32_bf16(a[mt], bfr[nt], C[mt][nt], 0, 0, 0);
  }

  // C/D layout: col = lane&15 (lr), row = quad*4 + v. Scatter each element to acc[mo[row]].
  // Per atomic instruction: 4 quads -> 4 scattered rows, 16 consecutive cols (64B segments).
#pragma unroll
  for (int mt = 0; mt < 2; ++mt)
#pragma unroll
    for (int v = 0; v < 4; ++v) {
      int lrow = wm + mt * 16 + quad * 4 + v;
      float* dst = acc + (size_t)srow[lrow] * CD + wn + lr;
#pragma unroll
      for (int nt = 0; nt < 4; ++nt)
        atomicAdd(dst + nt * 16, C[mt][nt][v]);
    }
}

// ---------------- per-channel BN stats over acc (sum, sumsq) ----------------
__global__ __launch_bounds__(256) void k_stats(const float* __restrict__ acc,
                                               float* __restrict__ stats) {
  const int t = threadIdx.x;
  const long total = (long)NPTS * CD / 4;
  const long stride = (long)gridDim.x * 256;
  long idx = (long)blockIdx.x * 256 + t;
  float s0 = 0.f, s1 = 0.f, s2 = 0.f, s3 = 0.f;
  float q0 = 0.f, q1 = 0.f, q2 = 0.f, q3 = 0.f;
  for (long i = idx; i < total; i += stride) {
    float4 a = *(const float4*)(acc + i * 4);
    s0 += a.x; q0 += a.x * a.x;
    s1 += a.y; q1 += a.y * a.y;
    s2 += a.z; q2 += a.z * a.z;
    s3 += a.w; q3 += a.w * a.w;
  }
  __shared__ float sh[2048];
  sh[t * 8 + 0] = s0; sh[t * 8 + 1] = s1; sh[t * 8 + 2] = s2; sh[t * 8 + 3] = s3;
  sh[t * 8 + 4] = q0; sh[t * 8 + 5] = q1; sh[t * 8 + 6] = q2; sh[t * 8 + 7] = q3;
  __syncthreads();
  if (t < 32) {
#pragma unroll
    for (int j = 0; j < 4; ++j) {
      float a = 0.f, qq = 0.f;
#pragma unroll
      for (int g = 0; g < 8; ++g) {
        a += sh[(t + g * 32) * 8 + j];
        qq += sh[(t + g * 32) * 8 + 4 + j];
      }
      atomicAdd(&stats[t * 4 + j], a);
      atomicAdd(&stats[128 + t * 4 + j], qq);
    }
  }
}

// ---------------- BN finalize / apply ----------------
__global__ void k_finalize(const float* __restrict__ stats, const float* __restrict__ gamma,
                           const float* __restrict__ beta, float* __restrict__ scsh) {
  int c = threadIdx.x;
  float mean = stats[c] * (1.f / NPTS);
  float var = stats[128 + c] * (1.f / NPTS) - mean * mean;
  float sc = rsqrtf(var + 1e-5f) * gamma[c];
  scsh[c] = sc;
  scsh[128 + c] = beta[c] - mean * sc;
}

__device__ __forceinline__ float elu(float v) { return v > 0.f ? v : expf(v) - 1.f; }

// reads acc, writes bf16 mid activations, and re-zeros acc for the next conv
__global__ __launch_bounds__(256) void k_apply_mid(float* __restrict__ acc,
                                                   const float* __restrict__ scsh,
                                                   u16* __restrict__ y) {
  long i = ((long)blockIdx.x * 256 + threadIdx.x) * 4;
  int c = (int)(i & 127);
  float4 a = *(const float4*)(acc + i);
  float r0 = elu(a.x * scsh[c] + scsh[128 + c]);
  float r1 = elu(a.y * scsh[c + 1] + scsh[129 + c]);
  float r2 = elu(a.z * scsh[c + 2] + scsh[130 + c]);
  float r3 = elu(a.w * scsh[c + 3] + scsh[131 + c]);
  uint2 v;
  v.x = f2bf(r0) | ((u32)f2bf(r1) << 16);
  v.y = f2bf(r2) | ((u32)f2bf(r3) << 16);
  *(uint2*)(y + i) = v;
  *(float4*)(acc + i) = make_float4(0.f, 0.f, 0.f, 0.f);
}

__global__ __launch_bounds__(256) void k_apply_final(const float* __restrict__ acc,
                                                     const float* __restrict__ scsh,
                                                     const float* __restrict__ x,
                                                     float* __restrict__ out) {
  long i = ((long)blockIdx.x * 256 + threadIdx.x) * 4;
  int c = (int)(i & 127);
  float4 a = *(const float4*)(acc + i);
  float4 rx = *(const float4*)(x + i);
  float4 o;
  o.x = elu(a.x * scsh[c] + scsh[128 + c] + rx.x);
  o.y = elu(a.y * scsh[c + 1] + scsh[129 + c] + rx.y);
  o.z = elu(a.z * scsh[c + 2] + scsh[130 + c] + rx.z);
  o.w = elu(a.w * scsh[c + 3] + scsh[131 + c] + rx.w);
  *(float4*)(out + i) = o;
}

// ---------------- host ----------------
extern "C" void kernel_launch(void* const* d_in, const int* in_sizes, int n_in,
                              void* d_out, int out_size, void* d_ws, size_t ws_size,
                              hipStream_t stream) {
  const float* x = (const float*)d_in[0];
  const float* W1 = (const float*)d_in[1];
  const float* g1 = (const float*)d_in[2];
  const float* b1 = (const float*)d_in[3];
  const float* W2 = (const float*)d_in[4];
  const float* g2 = (const float*)d_in[5];
  const float* b2 = (const float*)d_in[6];
  const int* m1i = (const int*)d_in[7];
  const int* m1o = (const int*)d_in[8];
  const int* m2i = (const int*)d_in[9];
  const int* m2o = (const int*)d_in[10];
  float* out = (float*)d_out;

  char* base = (char*)d_ws;
  size_t off = 0;
  auto alloc = [&](size_t bytes) -> void* {
    void* r = base + off;
    off = (off + bytes + 255) & ~(size_t)255;
    return r;
  };
  // xb doubles as the mid-activation buffer (xb dead after conv1's gemm).
  u16* xb = (u16*)alloc((size_t)NPTS * CD * 2);
  u16* Wb1 = (u16*)alloc((size_t)KOFF * CD * CD * 2);
  u16* Wb2 = (u16*)alloc((size_t)KOFF * CD * CD * 2);
  float* acc = (float*)alloc((size_t)NPTS * CD * 4);
  float* stats = (float*)alloc(256 * 4);
  float* scsh = (float*)alloc(256 * 4);

  hipMemsetAsync(acc, 0, (size_t)NPTS * CD * 4, stream);
  k_convert_x<<<(NPTS * CD) / 2048, 256, 0, stream>>>(x, xb);
  k_convert_w<<<(KOFF * 2048 + 255) / 256, 256, 0, stream>>>(W1, Wb1);
  k_convert_w<<<(KOFF * 2048 + 255) / 256, 256, 0, stream>>>(W2, Wb2);

  // conv1: single gather-GEMM-atomic-scatter dispatch over all 27 offsets
  k_gemm4<<<KOFF * 1024, 256, 0, stream>>>(xb, Wb1, m1i, m1o, acc);
  hipMemsetAsync(stats, 0, 1024, stream);
  k_stats<<<2048, 256, 0, stream>>>(acc, stats);
  k_finalize<<<1, 128, 0, stream>>>(stats, g1, b1, scsh);
  k_apply_mid<<<(NPTS * CD) / 1024, 256, 0, stream>>>(acc, scsh, xb);

  // conv2
  k_gemm4<<<KOFF * 1024, 256, 0, stream>>>(xb, Wb2, m2i, m2o, acc);
  hipMemsetAsync(stats, 0, 1024, stream);
  k_stats<<<2048, 256, 0, stream>>>(acc, stats);
  k_finalize<<<1, 128, 0, stream>>>(stats, g2, b2, scsh);
  k_apply_final<<<(NPTS * CD) / 1024, 256, 0, stream>>>(acc, scsh, x, out);
}

// Round 4
// 1335.349 us; speedup vs baseline: 1.5191x; 1.5191x over previous
//
#include <hip/hip_runtime.h>

typedef unsigned short u16;
typedef unsigned int u32;

#define NPTS 131072
#define CD 128
#define KOFF 27
#define MMAP 65536
#define LDAB 136   // LDS row stride (u16) for A/B tiles: 128+8
#define LDC 132    // LDS row stride (u16) for C repack: keeps store banks <=2-way

__device__ __forceinline__ u16 f2bf(float f) {  // f32 -> bf16 RNE
  u32 u = __float_as_uint(f);
  u32 r = (u + 0x7fffu + ((u >> 16) & 1u)) >> 16;
  return (u16)r;
}

typedef __attribute__((ext_vector_type(8))) short bf16x8;
typedef __attribute__((ext_vector_type(4))) float f32x4;

// ---------------- dtype conversion ----------------
__global__ __launch_bounds__(256) void k_convert_x(const float* __restrict__ x,
                                                   u16* __restrict__ xb) {
  long i = ((long)blockIdx.x * 256 + threadIdx.x) * 8;
  float4 a = *(const float4*)(x + i);
  float4 b = *(const float4*)(x + i + 4);
  uint4 v;
  v.x = f2bf(a.x) | ((u32)f2bf(a.y) << 16);
  v.y = f2bf(a.z) | ((u32)f2bf(a.w) << 16);
  v.z = f2bf(b.x) | ((u32)f2bf(b.y) << 16);
  v.w = f2bf(b.z) | ((u32)f2bf(b.w) << 16);
  *(uint4*)(xb + i) = v;
}

// W [K][ci][co] f32 -> Wb [K][co][ci] bf16
__global__ __launch_bounds__(256) void k_convert_w(const float* __restrict__ W,
                                                   u16* __restrict__ Wb) {
  int idx = blockIdx.x * 256 + threadIdx.x;
  if (idx >= KOFF * 2048) return;
  int k = idx >> 11;
  int rem = idx & 2047;
  int co = rem >> 4;
  int cc = rem & 15;
  const float* ws = W + (long)k * (CD * CD) + (long)(cc * 8) * CD + co;
  u16 t[8];
#pragma unroll
  for (int j = 0; j < 8; ++j) t[j] = f2bf(ws[j * CD]);
  uint4 v;
  v.x = t[0] | ((u32)t[1] << 16);
  v.y = t[2] | ((u32)t[3] << 16);
  v.z = t[4] | ((u32)t[5] << 16);
  v.w = t[6] | ((u32)t[7] << 16);
  ((uint4*)Wb)[idx] = v;
}

// ---------------- batched counting sort: all P passes of one conv in one set ----------------
// bins are pass-segmented: hist[p*NPTS + row]; offs has per-pass stride NPTS+1.
__global__ __launch_bounds__(256) void k_hist2(const int* __restrict__ mo,
                                               u32* __restrict__ hist, int bpp) {
  int p = blockIdx.x / bpp;
  int i = blockIdx.x * 256 + threadIdx.x;
  atomicAdd(&hist[(size_t)p * NPTS + mo[i]], 1u);
}

__global__ __launch_bounds__(256) void k_scanA2(const u32* __restrict__ hist,
                                                u32* __restrict__ offs,
                                                u32* __restrict__ bsum) {
  __shared__ u32 sh[256];
  int t = threadIdx.x, b = blockIdx.x;
  int p = b >> 9, rblk = b & 511;
  u32 v = hist[(size_t)p * NPTS + rblk * 256 + t];
  u32 run = v;
  sh[t] = run;
  __syncthreads();
  for (int d = 1; d < 256; d <<= 1) {
    u32 y = (t >= d) ? sh[t - d] : 0u;
    __syncthreads();
    run += y;
    sh[t] = run;
    __syncthreads();
  }
  offs[(size_t)p * (NPTS + 1) + rblk * 256 + t] = run - v;
  if (t == 255) bsum[b] = run;
}

__global__ __launch_bounds__(512) void k_scanB2(u32* __restrict__ bsum) {
  __shared__ u32 sh[512];
  int t = threadIdx.x;
  u32* bp = bsum + blockIdx.x * 512;
  u32 v = bp[t];
  u32 run = v;
  sh[t] = run;
  __syncthreads();
  for (int d = 1; d < 512; d <<= 1) {
    u32 y = (t >= d) ? sh[t - d] : 0u;
    __syncthreads();
    run += y;
    sh[t] = run;
    __syncthreads();
  }
  bp[t] = run - v;
}

__global__ __launch_bounds__(256) void k_scanC2(u32* __restrict__ offs,
                                                const u32* __restrict__ bsum, int kcnt) {
  int t = threadIdx.x, b = blockIdx.x;
  int p = b >> 9, rblk = b & 511;
  size_t base = (size_t)p * (NPTS + 1);
  offs[base + rblk * 256 + t] += bsum[b];
  if (rblk == 0 && t == 0) {
    int kc = KOFF - p * kcnt;
    if (kc > kcnt) kc = kcnt;
    offs[base + NPTS] = (u32)kc * MMAP;
  }
}

__global__ __launch_bounds__(256) void k_rank2(const int* __restrict__ mo,
                                               const u32* __restrict__ offs,
                                               u32* __restrict__ cur,
                                               u32* __restrict__ rank, int bpp) {
  int p = blockIdx.x / bpp;
  int i = blockIdx.x * 256 + threadIdx.x;
  int o = mo[i];
  rank[i] = offs[(size_t)p * (NPTS + 1) + o] + atomicAdd(&cur[(size_t)p * NPTS + o], 1u);
}

// ---------------- gather-GEMM, natural (k, m-tile) order, rank-scatter rows ----------------
__global__ __launch_bounds__(256) void k_gemm3(const u16* __restrict__ src,
                                               const u16* __restrict__ Wb,
                                               const int* __restrict__ mi,   // pass base
                                               const u32* __restrict__ rank, // pass base
                                               u16* __restrict__ contrib,
                                               int kbase) {
  __shared__ u16 As[64 * LDAB];
  __shared__ u16 Bs[128 * LDAB];
  __shared__ u32 sin[64];
  __shared__ u32 srow[64];
  const int t = threadIdx.x;
  const int b = blockIdx.x;
  const int klocal = b >> 10;
  const int i0 = klocal * MMAP + (b & 1023) * 64;

  if (t < 64) {
    sin[t] = (u32)mi[i0 + t];
    srow[t] = rank[i0 + t];
  }
  const uint4* wsrc = (const uint4*)(Wb + (long)(kbase + klocal) * (CD * CD));
#pragma unroll
  for (int i = 0; i < 8; ++i) {
    int q = i * 256 + t;
    int co = q >> 4, cc = q & 15;
    *(uint4*)&Bs[co * LDAB + cc * 8] = wsrc[q];
  }
  __syncthreads();
#pragma unroll
  for (int i = 0; i < 4; ++i) {
    int q = i * 256 + t;
    int r = q >> 4, cc = q & 15;
    long row = sin[r];
    *(uint4*)&As[r * LDAB + cc * 8] = ((const uint4*)(src + row * CD))[cc];
  }
  __syncthreads();

  const int wave = t >> 6, lane = t & 63;
  const int lr = lane & 15, quad = lane >> 4;
  const int wm = (wave & 1) * 32;
  const int wn = (wave >> 1) * 64;
  f32x4 acc[2][4] = {};
#pragma unroll
  for (int kk = 0; kk < 4; ++kk) {
    bf16x8 a[2], bfr[4];
#pragma unroll
    for (int mt = 0; mt < 2; ++mt)
      a[mt] = *(const bf16x8*)&As[(wm + mt * 16 + lr) * LDAB + (kk * 4 + quad) * 8];
#pragma unroll
    for (int nt = 0; nt < 4; ++nt)
      bfr[nt] = *(const bf16x8*)&Bs[(wn + nt * 16 + lr) * LDAB + (kk * 4 + quad) * 8];
#pragma unroll
    for (int mt = 0; mt < 2; ++mt)
#pragma unroll
      for (int nt = 0; nt < 4; ++nt)
        acc[mt][nt] = __builtin_amdgcn_mfma_f32_16x16x32_bf16(a[mt], bfr[nt], acc[mt][nt], 0, 0, 0);
  }

  // repack C through LDS (C/D layout: col = lane&15, row = quad*4+reg), then coalesced row stores
  __syncthreads();
  u16* Cs = As;  // reuse: 64*132 u16 = 16.9KB <= As 17.4KB
#pragma unroll
  for (int mt = 0; mt < 2; ++mt)
#pragma unroll
    for (int v = 0; v < 4; ++v) {
      int slot = wm + mt * 16 + quad * 4 + v;
#pragma unroll
      for (int nt = 0; nt < 4; ++nt)
        Cs[slot * LDC + wn + nt * 16 + lr] = f2bf(acc[mt][nt][v]);
    }
  __syncthreads();
#pragma unroll
  for (int i = 0; i < 4; ++i) {
    int q = i * 256 + t;
    int r = q >> 4, cc = q & 15;
    size_t rk = srow[r];
    *(uint4*)(contrib + rk * CD + cc * 8) = *(const uint4*)&Cs[r * LDC + cc * 8];
  }
}

// ---------------- segmented reduce v5: entry-parallel (4 quads = 4 entries in flight) ----------
// Whole wave processes one row at a time; quad q sums entries q, q+4, q+8... (one masked 1KB
// wave-load covers len<=4, the common case). Cross-quad shfl_xor reduce, then full-wave
// coalesced 512B acc RMW. 17 offs preloaded once per wave.
__global__ __launch_bounds__(256, 8) void k_segreduce5(const u16* __restrict__ contrib,
                                                       const u32* __restrict__ offs,
                                                       float* __restrict__ acc,
                                                       float* __restrict__ stats,
                                                       int first, int last) {
  const int wave = threadIdx.x >> 6, lane = threadIdx.x & 63;
  const int W = blockIdx.x * 4 + wave;  // 8192 waves, 16 rows each
  const int quad = lane >> 4, sub = lane & 15;
  const int r0 = W * 16;
  u32 ld_off = offs[r0 + (lane < 17 ? lane : 16)];
  float s0a = 0.f, s1a = 0.f, q0a = 0.f, q1a = 0.f;  // stats for this lane's 2 channels
#pragma unroll 2
  for (int b = 0; b < 16; ++b) {
    const int row = r0 + b;
    const u32 e0 = __shfl(ld_off, b);
    const u32 e1 = __shfl(ld_off, b + 1);
    const int len = (int)(e1 - e0);
    float v[8];
#pragma unroll
    for (int j = 0; j < 8; ++j) v[j] = 0.f;
    const u32* cp = (const u32*)(contrib + (size_t)e0 * CD) + sub * 4;
    for (int i = quad; i < len; i += 4) {
      uint4 d = *(const uint4*)(cp + (size_t)i * 64);
      v[0] += __uint_as_float(d.x << 16);
      v[1] += __uint_as_float(d.x & 0xffff0000u);
      v[2] += __uint_as_float(d.y << 16);
      v[3] += __uint_as_float(d.y & 0xffff0000u);
      v[4] += __uint_as_float(d.z << 16);
      v[5] += __uint_as_float(d.z & 0xffff0000u);
      v[6] += __uint_as_float(d.w << 16);
      v[7] += __uint_as_float(d.w & 0xffff0000u);
    }
#pragma unroll
    for (int j = 0; j < 8; ++j) {
      v[j] += __shfl_xor(v[j], 16);
      v[j] += __shfl_xor(v[j], 32);
    }
    // lane writes channels sub*8 + quad*2 + {0,1}
    float2* ap = (float2*)(acc + (size_t)row * CD) + (sub * 4 + quad);
    float c0 = v[2 * quad], c1 = v[2 * quad + 1];
    if (!first) {
      float2 pv = *ap;
      c0 += pv.x;
      c1 += pv.y;
    }
    *ap = make_float2(c0, c1);
    if (last) {
      s0a += c0;
      q0a += c0 * c0;
      s1a += c1;
      q1a += c1 * c1;
    }
  }
  if (last) {
    __shared__ float sh[256][4];
    sh[threadIdx.x][0] = s0a;
    sh[threadIdx.x][1] = s1a;
    sh[threadIdx.x][2] = q0a;
    sh[threadIdx.x][3] = q1a;
    __syncthreads();
    if (threadIdx.x < 64) {
      int l = threadIdx.x;
      int c = (l & 15) * 8 + (l >> 4) * 2;
      float S0 = sh[l][0] + sh[64 + l][0] + sh[128 + l][0] + sh[192 + l][0];
      float S1 = sh[l][1] + sh[64 + l][1] + sh[128 + l][1] + sh[192 + l][1];
      float Q0 = sh[l][2] + sh[64 + l][2] + sh[128 + l][2] + sh[192 + l][2];
      float Q1 = sh[l][3] + sh[64 + l][3] + sh[128 + l][3] + sh[192 + l][3];
      atomicAdd(&stats[c], S0);
      atomicAdd(&stats[c + 1], S1);
      atomicAdd(&stats[128 + c], Q0);
      atomicAdd(&stats[128 + c + 1], Q1);
    }
  }
}

// ---------------- BN finalize / apply ----------------
__global__ void k_finalize(const float* __restrict__ stats, const float* __restrict__ gamma,
                           const float* __restrict__ beta, float* __restrict__ scsh) {
  int c = threadIdx.x;
  float mean = stats[c] * (1.f / NPTS);
  float var = stats[128 + c] * (1.f / NPTS) - mean * mean;
  float sc = rsqrtf(var + 1e-5f) * gamma[c];
  scsh[c] = sc;
  scsh[128 + c] = beta[c] - mean * sc;
}

__device__ __forceinline__ float elu(float v) { return v > 0.f ? v : expf(v) - 1.f; }

__global__ __launch_bounds__(256) void k_apply_mid(const float* __restrict__ acc,
                                                   const float* __restrict__ scsh,
                                                   u16* __restrict__ y) {
  long i = ((long)blockIdx.x * 256 + threadIdx.x) * 4;
  int c = (int)(i & 127);
  float4 a = *(const float4*)(acc + i);
  float r0 = elu(a.x * scsh[c] + scsh[128 + c]);
  float r1 = elu(a.y * scsh[c + 1] + scsh[129 + c]);
  float r2 = elu(a.z * scsh[c + 2] + scsh[130 + c]);
  float r3 = elu(a.w * scsh[c + 3] + scsh[131 + c]);
  uint2 v;
  v.x = f2bf(r0) | ((u32)f2bf(r1) << 16);
  v.y = f2bf(r2) | ((u32)f2bf(r3) << 16);
  *(uint2*)(y + i) = v;
}

__global__ __launch_bounds__(256) void k_apply_final(const float* __restrict__ acc,
                                                     const float* __restrict__ scsh,
                                                     const float* __restrict__ x,
                                                     float* __restrict__ out) {
  long i = ((long)blockIdx.x * 256 + threadIdx.x) * 4;
  int c = (int)(i & 127);
  float4 a = *(const float4*)(acc + i);
  float4 rx = *(const float4*)(x + i);
  float4 o;
  o.x = elu(a.x * scsh[c] + scsh[128 + c] + rx.x);
  o.y = elu(a.y * scsh[c + 1] + scsh[129 + c] + rx.y);
  o.z = elu(a.z * scsh[c + 2] + scsh[130 + c] + rx.z);
  o.w = elu(a.w * scsh[c + 3] + scsh[131 + c] + rx.w);
  *(float4*)(out + i) = o;
}

// ---------------- host ----------------
extern "C" void kernel_launch(void* const* d_in, const int* in_sizes, int n_in,
                              void* d_out, int out_size, void* d_ws, size_t ws_size,
                              hipStream_t stream) {
  const float* x = (const float*)d_in[0];
  const float* W1 = (const float*)d_in[1];
  const float* g1 = (const float*)d_in[2];
  const float* b1 = (const float*)d_in[3];
  const float* W2 = (const float*)d_in[4];
  const float* g2 = (const float*)d_in[5];
  const float* b2 = (const float*)d_in[6];
  const int* m1i = (const int*)d_in[7];
  const int* m1o = (const int*)d_in[8];
  const int* m2i = (const int*)d_in[9];
  const int* m2o = (const int*)d_in[10];
  float* out = (float*)d_out;

  char* base = (char*)d_ws;
  size_t off = 0;
  auto alloc = [&](size_t bytes) -> void* {
    void* r = base + off;
    off = (off + bytes + 255) & ~(size_t)255;
    return r;
  };
  // xb doubles as the mid-activation buffer (xb dead after conv1's last gemm pass).
  u16* xb = (u16*)alloc((size_t)NPTS * CD * 2);
  u16* Wb1 = (u16*)alloc((size_t)KOFF * CD * CD * 2);
  u16* Wb2 = (u16*)alloc((size_t)KOFF * CD * CD * 2);
  float* acc = (float*)alloc((size_t)NPTS * CD * 4);
  float* stats = (float*)alloc(256 * 4);
  float* scsh = (float*)alloc(256 * 4);

  // choose kcnt (k-offsets per pass) so contrib + pass-segmented sort buffers fit
  int kcnt = 1, P = KOFF;
  for (int kc = KOFF; kc >= 1; --kc) {
    int Pp = (KOFF + kc - 1) / kc;
    size_t need = off + 2 * (size_t)Pp * NPTS * 4 + 512         // hist+cur
                  + (size_t)Pp * (NPTS + 1) * 4 + 256           // offs
                  + (size_t)Pp * 512 * 4 + 256                  // bsum
                  + (size_t)KOFF * MMAP * 4 + 256               // rank
                  + (size_t)kc * MMAP * CD * 2 + 4096;          // contrib
    if (need <= ws_size) {
      kcnt = kc;
      P = Pp;
      break;
    }
  }
  u32* hist = (u32*)alloc((size_t)P * NPTS * 4);
  u32* cur = (u32*)alloc((size_t)P * NPTS * 4);  // contiguous with hist for one memset
  u32* offs = (u32*)alloc((size_t)P * (NPTS + 1) * 4);
  u32* bsum = (u32*)alloc((size_t)P * 512 * 4);
  u32* rank = (u32*)alloc((size_t)KOFF * MMAP * 4);
  u16* contrib = (u16*)alloc((size_t)kcnt * MMAP * CD * 2);

  k_convert_x<<<(NPTS * CD) / 2048, 256, 0, stream>>>(x, xb);
  k_convert_w<<<(KOFF * 2048 + 255) / 256, 256, 0, stream>>>(W1, Wb1);
  k_convert_w<<<(KOFF * 2048 + 255) / 256, 256, 0, stream>>>(W2, Wb2);

  const int nb = (KOFF * MMAP) / 256;       // hist/rank grid
  const int bpp = kcnt * (MMAP / 256);      // blocks per pass

  auto run_conv = [&](const u16* srcm, const u16* Wbm, const int* mi, const int* mo) {
    hipMemsetAsync(stats, 0, 1024, stream);
    hipMemsetAsync(hist, 0, 2 * (size_t)P * NPTS * 4, stream);
    k_hist2<<<nb, 256, 0, stream>>>(mo, hist, bpp);
    k_scanA2<<<512 * P, 256, 0, stream>>>(hist, offs, bsum);
    k_scanB2<<<P, 512, 0, stream>>>(bsum);
    k_scanC2<<<512 * P, 256, 0, stream>>>(offs, bsum, kcnt);
    k_rank2<<<nb, 256, 0, stream>>>(mo, offs, cur, rank, bpp);
    for (int p = 0; p < P; ++p) {
      int kc = (KOFF - p * kcnt < kcnt) ? KOFF - p * kcnt : kcnt;
      k_gemm3<<<kc * 1024, 256, 0, stream>>>(srcm, Wbm, mi + (long)p * kcnt * MMAP,
                                             rank + (long)p * kcnt * MMAP, contrib, p * kcnt);
      k_segreduce5<<<2048, 256, 0, stream>>>(contrib, offs + (size_t)p * (NPTS + 1), acc, stats,
                                             p == 0 ? 1 : 0, p == P - 1 ? 1 : 0);
    }
  };

  run_conv(xb, Wb1, m1i, m1o);
  k_finalize<<<1, 128, 0, stream>>>(stats, g1, b1, scsh);
  k_apply_mid<<<(NPTS * CD) / 1024, 256, 0, stream>>>(acc, scsh, xb);

  run_conv(xb, Wb2, m2i, m2o);
  k_finalize<<<1, 128, 0, stream>>>(stats, g2, b2, scsh);
  k_apply_final<<<(NPTS * CD) / 1024, 256, 0, stream>>>(acc, scsh, x, out);
}